// Round 25
// baseline (320.098 us; speedup 1.0000x reference)
//
#include <hip/hip_runtime.h>

#define T_SEQ 2048
#define C_DIM 1024
#define HD 64

typedef __attribute__((ext_vector_type(8))) short short8;
typedef __attribute__((ext_vector_type(4))) float f32x4;
typedef __attribute__((ext_vector_type(4))) unsigned int uint4v;

extern "C" __device__ float __ocml_native_exp2_f32(float);

__device__ __forceinline__ unsigned short f2bf(float f) {
  unsigned int u = __builtin_bit_cast(unsigned int, f);
  u += 0x7fffu + ((u >> 16) & 1u);
  return (unsigned short)(u >> 16);
}

__device__ __forceinline__ unsigned cvt_pk_bf16(float lo, float hi) {
  unsigned r;
  asm("v_cvt_pk_bf16_f32 %0, %1, %2" : "=v"(r) : "v"(lo), "v"(hi));
  return r;
}

// async global->LDS, 16B per lane. LDS dest = wave-uniform base + lane*16.
__device__ __forceinline__ void gload_lds16(const void* g, void* l) {
  __builtin_amdgcn_global_load_lds(
      (const __attribute__((address_space(1))) void*)g,
      (__attribute__((address_space(3))) void*)l, 16, 0, 0);
}

// ---- merged prep: blocks [0,4096) conv x->bf16; [4096,8192) transpose
// W_attn K-slice; [8192,12288) transpose W_proj. Branch is block-uniform.
__global__ __launch_bounds__(256) void prep(
    const float* __restrict__ x, unsigned short* __restrict__ xb,
    const float* __restrict__ W_attn, unsigned short* __restrict__ Wkt,
    const float* __restrict__ W_proj, unsigned short* __restrict__ Wpt) {
  int b = blockIdx.x;
  if (b < 4096) {
    size_t idx = ((size_t)b * 256 + threadIdx.x) * 8;
    const f32x4* p = (const f32x4*)(x + idx);
    f32x4 a = p[0], c = p[1];
    short8 s;
#pragma unroll
    for (int i = 0; i < 4; ++i) {
      s[i]     = (short)f2bf(a[i]);
      s[i + 4] = (short)f2bf(c[i]);
    }
    *(short8*)(xb + idx) = s;
  } else {
    __shared__ float tile[16][17];
    int b2 = b - 4096;
    const float* src;
    unsigned short* dst;
    int src_ld, col_off;
    if (b2 < 4096) { src = W_attn; dst = Wkt; src_ld = 3072; col_off = 1024; }
    else { b2 -= 4096; src = W_proj; dst = Wpt; src_ld = 1024; col_off = 0; }
    const int tx = threadIdx.x & 15, ty = threadIdx.x >> 4;
    const int bx = b2 & 63, by = b2 >> 6;
    int n = bx * 16 + tx;                    // src col (contiguous read)
    int k = by * 16 + ty;                    // src row
    tile[ty][tx] = src[(size_t)k * src_ld + col_off + n];
    __syncthreads();
    int nn = bx * 16 + ty;                   // dst row
    int kk = by * 16 + tx;                   // dst col (contiguous write)
    dst[(size_t)nn * C_DIM + kk] = f2bf(tile[tx][ty]);
  }
}

// ---- GEMM1: Khb[bh][t][d] and Vt[bh][d][t] (bf16) = xb(bf16) @ Wkt^T + bias
// Double-buffered global_load_lds staging, ONE barrier per K-step.
__global__ __launch_bounds__(256) void gemm_xw(
    const unsigned short* __restrict__ A, const unsigned short* __restrict__ Bt,
    const float* __restrict__ bias, unsigned short* __restrict__ out,
    unsigned short* __restrict__ vt) {
  __shared__ unsigned short Als[2][128 * 32];
  __shared__ unsigned short Bls[2][128 * 32];
  const int tid = threadIdx.x;
  const int l = tid & 63, w = tid >> 6;
  const int wr = w >> 1, wc = w & 1;
  const int rb = blockIdx.x * 128, cb = blockIdx.y * 128;
  const int brow = tid >> 2, bhalf = (tid & 3) * 8;
  f32x4 acc[4][4] = {};

#define STAGE_XW(BUF, KB)                                                     \
  do {                                                                        \
    gload_lds16(A + (size_t)(rb + brow) * 1024 + (KB) + bhalf,                \
                &Als[BUF][(size_t)w * 512]);                                  \
    gload_lds16(A + (size_t)(rb + 64 + brow) * 1024 + (KB) + bhalf,           \
                &Als[BUF][2048 + (size_t)w * 512]);                           \
    gload_lds16(Bt + (size_t)(cb + brow) * 1024 + (KB) + bhalf,               \
                &Bls[BUF][(size_t)w * 512]);                                  \
    gload_lds16(Bt + (size_t)(cb + 64 + brow) * 1024 + (KB) + bhalf,          \
                &Bls[BUF][2048 + (size_t)w * 512]);                           \
  } while (0)

  STAGE_XW(0, 0);
  int cur = 0;
  for (int kb = 0; kb < 1024; kb += 32) {
    __syncthreads();                       // drains buf[cur] loads; fences reads
    if (kb + 32 < 1024) STAGE_XW(cur ^ 1, kb + 32);
    short8 af[4], bfr[4];
#pragma unroll
    for (int m = 0; m < 4; ++m)
      af[m] = *(const short8*)&Als[cur][(wr * 64 + m * 16 + (l & 15)) * 32 + (l >> 4) * 8];
#pragma unroll
    for (int n = 0; n < 4; ++n)
      bfr[n] = *(const short8*)&Bls[cur][(wc * 64 + n * 16 + (l & 15)) * 32 + (l >> 4) * 8];
#pragma unroll
    for (int m = 0; m < 4; ++m)
#pragma unroll
      for (int n = 0; n < 4; ++n)
        acc[m][n] = __builtin_amdgcn_mfma_f32_16x16x32_bf16(af[m], bfr[n], acc[m][n], 0, 0, 0);
    cur ^= 1;
  }
#undef STAGE_XW

  const int rg = (l >> 4) * 4, cg = l & 15;
#pragma unroll
  for (int m = 0; m < 4; ++m)
#pragma unroll
    for (int n = 0; n < 4; ++n) {
      int col = cb + wc * 64 + n * 16 + cg;
      float bv = bias[col];
      int row0 = rb + wr * 64 + m * 16 + rg;
      unsigned short e0 = f2bf(acc[m][n][0] + bv);
      unsigned short e1 = f2bf(acc[m][n][1] + bv);
      unsigned short e2 = f2bf(acc[m][n][2] + bv);
      unsigned short e3 = f2bf(acc[m][n][3] + bv);
      size_t bhd = (size_t)((row0 >> 11) * 16 + (col >> 6));
      size_t kidx = (bhd * T_SEQ + (row0 & 2047)) * HD + (col & 63);
      out[kidx]          = e0;
      out[kidx + HD]     = e1;
      out[kidx + 2 * HD] = e2;
      out[kidx + 3 * HD] = e3;
      unsigned long long pv = (unsigned long long)e0 | ((unsigned long long)e1 << 16)
                            | ((unsigned long long)e2 << 32) | ((unsigned long long)e3 << 48);
      *(unsigned long long*)&vt[(bhd * HD + (col & 63)) * T_SEQ + (row0 & 2047)] = pv;
    }
}

// ---- GEMM2: out[8192][1024] (f32) = y(bf16) @ Wpt^T + bias
// Double-buffered global_load_lds staging, ONE barrier per K-step.
__global__ __launch_bounds__(256) void gemm_yw(
    const unsigned short* __restrict__ A, const unsigned short* __restrict__ Bt,
    const float* __restrict__ bias, float* __restrict__ out) {
  __shared__ unsigned short Als[2][128 * 32];
  __shared__ unsigned short Bls[2][128 * 32];
  const int tid = threadIdx.x;
  const int l = tid & 63, w = tid >> 6;
  const int wr = w >> 1, wc = w & 1;
  const int rb = blockIdx.x * 128, cb = blockIdx.y * 128;
  const int brow = tid >> 2, bhalf = (tid & 3) * 8;
  f32x4 acc[4][4] = {};

#define STAGE_YW(BUF, KB)                                                     \
  do {                                                                        \
    gload_lds16(A + (size_t)(rb + brow) * 1024 + (KB) + bhalf,                \
                &Als[BUF][(size_t)w * 512]);                                  \
    gload_lds16(A + (size_t)(rb + 64 + brow) * 1024 + (KB) + bhalf,           \
                &Als[BUF][2048 + (size_t)w * 512]);                           \
    gload_lds16(Bt + (size_t)(cb + brow) * 1024 + (KB) + bhalf,               \
                &Bls[BUF][(size_t)w * 512]);                                  \
    gload_lds16(Bt + (size_t)(cb + 64 + brow) * 1024 + (KB) + bhalf,          \
                &Bls[BUF][2048 + (size_t)w * 512]);                           \
  } while (0)

  STAGE_YW(0, 0);
  int cur = 0;
  for (int kb = 0; kb < 1024; kb += 32) {
    __syncthreads();
    if (kb + 32 < 1024) STAGE_YW(cur ^ 1, kb + 32);
    short8 af[4], bfr[4];
#pragma unroll
    for (int m = 0; m < 4; ++m)
      af[m] = *(const short8*)&Als[cur][(wr * 64 + m * 16 + (l & 15)) * 32 + (l >> 4) * 8];
#pragma unroll
    for (int n = 0; n < 4; ++n)
      bfr[n] = *(const short8*)&Bls[cur][(wc * 64 + n * 16 + (l & 15)) * 32 + (l >> 4) * 8];
#pragma unroll
    for (int m = 0; m < 4; ++m)
#pragma unroll
      for (int n = 0; n < 4; ++n)
        acc[m][n] = __builtin_amdgcn_mfma_f32_16x16x32_bf16(af[m], bfr[n], acc[m][n], 0, 0, 0);
    cur ^= 1;
  }
#undef STAGE_YW

  const int rg = (l >> 4) * 4, cg = l & 15;
#pragma unroll
  for (int m = 0; m < 4; ++m)
#pragma unroll
    for (int n = 0; n < 4; ++n) {
      int col = cb + wc * 64 + n * 16 + cg;
      float bv = bias[col];
#pragma unroll
      for (int r = 0; r < 4; ++r) {
        int row = rb + wr * 64 + m * 16 + rg + r;
        out[(size_t)row * 1024 + col] = acc[m][n][r] + bv;
      }
    }
}

// ---- Flash attention: FROZEN r13 dataflow. ONLY change: launch bounds
// (128,4)->(128,6): 24 waves/CU (6/SIMD), VGPR budget ~85 > natural 64.
__device__ __forceinline__ void sm_group(
    f32x4 (&s)[4], int qq, int kvb, bool needmask, int g,
    float& mrun, float& lrun, f32x4 (&yacc)[4],
    int src01, int src23, bool hi2, short8 (&pa)[2]) {
  if (needmask) {
    const int lim = qq - kvb;
#pragma unroll
    for (int b = 0; b < 4; ++b)
#pragma unroll
      for (int r = 0; r < 4; ++r)
        if (16 * b + 4 * g + r > lim) s[b][r] = -INFINITY;
  }
  float mt = fmaxf(fmaxf(s[0][0], s[0][1]), fmaxf(s[0][2], s[0][3]));
#pragma unroll
  for (int b = 1; b < 4; ++b)
    mt = fmaxf(mt, fmaxf(fmaxf(s[b][0], s[b][1]), fmaxf(s[b][2], s[b][3])));
  mt = fmaxf(mt, __shfl_xor(mt, 16));
  mt = fmaxf(mt, __shfl_xor(mt, 32));
  if (!__all(mt <= mrun + 11.5416f)) {   // 8 nats in log2 units
    float mn = fmaxf(mrun, mt);
    float al = __ocml_native_exp2_f32(mrun - mn);
    mrun = mn;
    lrun *= al;
    float a0 = __shfl(al, 4 * g + 0);
    float a1 = __shfl(al, 4 * g + 1);
    float a2 = __shfl(al, 4 * g + 2);
    float a3 = __shfl(al, 4 * g + 3);
#pragma unroll
    for (int nb = 0; nb < 4; ++nb) {
      yacc[nb][0] *= a0; yacc[nb][1] *= a1;
      yacc[nb][2] *= a2; yacc[nb][3] *= a3;
    }
  }
  float ps = 0.f;
  unsigned pk[4][2];
#pragma unroll
  for (int b = 0; b < 4; ++b) {
    float p0 = __ocml_native_exp2_f32(s[b][0] - mrun);
    float p1 = __ocml_native_exp2_f32(s[b][1] - mrun);
    float p2 = __ocml_native_exp2_f32(s[b][2] - mrun);
    float p3 = __ocml_native_exp2_f32(s[b][3] - mrun);
    ps += (p0 + p1) + (p2 + p3);
    pk[b][0] = cvt_pk_bf16(p0, p1);
    pk[b][1] = cvt_pk_bf16(p2, p3);
  }
  ps += __shfl_xor(ps, 16);
  ps += __shfl_xor(ps, 32);
  lrun += ps;
  {
    unsigned x0a = (unsigned)__shfl((int)pk[0][0], src01);
    unsigned x1a = (unsigned)__shfl((int)pk[1][0], src01);
    unsigned x0b = (unsigned)__shfl((int)pk[0][1], src01);
    unsigned x1b = (unsigned)__shfl((int)pk[1][1], src01);
    unsigned y0a = (unsigned)__shfl((int)pk[0][0], src23);
    unsigned y1a = (unsigned)__shfl((int)pk[1][0], src23);
    unsigned y0b = (unsigned)__shfl((int)pk[0][1], src23);
    unsigned y1b = (unsigned)__shfl((int)pk[1][1], src23);
    uint4v u;
    u.x = hi2 ? x1a : x0a;
    u.y = hi2 ? x1b : x0b;
    u.z = hi2 ? y1a : y0a;
    u.w = hi2 ? y1b : y0b;
    pa[0] = __builtin_bit_cast(short8, u);
  }
  {
    unsigned x0a = (unsigned)__shfl((int)pk[2][0], src01);
    unsigned x1a = (unsigned)__shfl((int)pk[3][0], src01);
    unsigned x0b = (unsigned)__shfl((int)pk[2][1], src01);
    unsigned x1b = (unsigned)__shfl((int)pk[3][1], src01);
    unsigned y0a = (unsigned)__shfl((int)pk[2][0], src23);
    unsigned y1a = (unsigned)__shfl((int)pk[3][0], src23);
    unsigned y0b = (unsigned)__shfl((int)pk[2][1], src23);
    unsigned y1b = (unsigned)__shfl((int)pk[3][1], src23);
    uint4v u;
    u.x = hi2 ? x1a : x0a;
    u.y = hi2 ? x1b : x0b;
    u.z = hi2 ? y1a : y0a;
    u.w = hi2 ? y1b : y0b;
    pa[1] = __builtin_bit_cast(short8, u);
  }
}

__global__ __launch_bounds__(128, 6) void attn_fwd(
    const unsigned short* __restrict__ Khb, const unsigned short* __restrict__ Vt,
    unsigned short* __restrict__ Y) {
  const int id = blockIdx.x;
  const int xcd = id & 7;
  const int r8  = id >> 3;             // 0..511
  const int bh  = xcd * 8 + (r8 & 7);
  const int chunk = 63 - (r8 >> 3);    // descending work within each XCD
  const int tid = threadIdx.x;
  const int w = tid >> 6;              // kv-split half
  const int l = tid & 63;
  const int i = l & 15, g = l >> 4;
  const unsigned short* kbase = Khb + (size_t)bh * T_SEQ * HD;
  const unsigned short* vbase = Vt + (size_t)bh * HD * T_SEQ;

  const int q0 = chunk * 32;
  const int qA = q0 + i, qB = q0 + 16 + i;
  const int nt = (q0 + 31) / 64 + 1;
  const int half = (nt + 1) >> 1;
  const int tBeg = w ? half : 0;
  const int tEnd = w ? nt : half;

  __shared__ float Ylds[32][68];
  __shared__ float Mlds[32];
  __shared__ float Llds[32];

  short8 qa0 = *(const short8*)(kbase + (size_t)qA * HD + g * 8);
  short8 qa1 = *(const short8*)(kbase + (size_t)qA * HD + 32 + g * 8);
  short8 qb0 = *(const short8*)(kbase + (size_t)qB * HD + g * 8);
  short8 qb1 = *(const short8*)(kbase + (size_t)qB * HD + 32 + g * 8);

  f32x4 ya[4] = {}, yb[4] = {};
  float mA = -INFINITY, lA = 0.f, mB = -INFINITY, lB = 0.f;

  const int src01 = i + ((g & 1) << 5);
  const int src23 = src01 + 16;
  const bool hi2 = (g >> 1) != 0;
  const float SCL = 0.18033688f;   // 0.125 * log2(e)

#pragma unroll 2
  for (int t = tBeg; t < tEnd; ++t) {
    const int kvb = t * 64;
    f32x4 sa[4], sb[4];
#pragma unroll
    for (int b = 0; b < 4; ++b) {
      const unsigned short* kp = kbase + (size_t)(kvb + 16 * b + i) * HD + g * 8;
      short8 k0 = *(const short8*)kp;
      short8 k1 = *(const short8*)(kp + 32);
      f32x4 acc = {};
      acc = __builtin_amdgcn_mfma_f32_16x16x32_bf16(k0, qa0, acc, 0, 0, 0);
      acc = __builtin_amdgcn_mfma_f32_16x16x32_bf16(k1, qa1, acc, 0, 0, 0);
      sa[b] = acc;
      f32x4 acc2 = {};
      acc2 = __builtin_amdgcn_mfma_f32_16x16x32_bf16(k0, qb0, acc2, 0, 0, 0);
      acc2 = __builtin_amdgcn_mfma_f32_16x16x32_bf16(k1, qb1, acc2, 0, 0, 0);
      sb[b] = acc2;
    }
#pragma unroll
    for (int b = 0; b < 4; ++b)
#pragma unroll
      for (int r = 0; r < 4; ++r) { sa[b][r] *= SCL; sb[b][r] *= SCL; }

    const bool needmask = (kvb + 63 > q0);
    short8 paA[2], paB[2];
    sm_group(sa, qA, kvb, needmask, g, mA, lA, ya, src01, src23, hi2, paA);
    sm_group(sb, qB, kvb, needmask, g, mB, lB, yb, src01, src23, hi2, paB);

#pragma unroll
    for (int c = 0; c < 2; ++c)
#pragma unroll
      for (int nb = 0; nb < 4; ++nb) {
        short8 vf = *(const short8*)(vbase + (size_t)(nb * 16 + i) * T_SEQ + kvb + c * 32 + g * 8);
        ya[nb] = __builtin_amdgcn_mfma_f32_16x16x32_bf16(paA[c], vf, ya[nb], 0, 0, 0);
        yb[nb] = __builtin_amdgcn_mfma_f32_16x16x32_bf16(paB[c], vf, yb[nb], 0, 0, 0);
      }
  }

  // wave1 deposits unnormalized partials
  if (w == 1) {
#pragma unroll
    for (int nb = 0; nb < 4; ++nb)
#pragma unroll
      for (int r = 0; r < 4; ++r) {
        Ylds[4 * g + r][nb * 16 + i]      = ya[nb][r];
        Ylds[16 + 4 * g + r][nb * 16 + i] = yb[nb][r];
      }
    if (l < 16) {
      Mlds[l]      = mA;
      Llds[l]      = lA;
      Mlds[16 + l] = mB;
      Llds[16 + l] = lB;
    }
  }
  __syncthreads();
  // wave0 merges and stores
  if (w == 0) {
    const int bb = bh >> 4, hh = bh & 15;
    size_t rowA = ((size_t)bb * T_SEQ + q0 + 4 * g) * C_DIM;
#pragma unroll
    for (int r = 0; r < 4; ++r) {
      float m0 = __shfl(mA, 4 * g + r);
      float l0 = __shfl(lA, 4 * g + r);
      float m1 = Mlds[4 * g + r];
      float l1 = Llds[4 * g + r];
      float mm = fmaxf(m0, m1);
      float e0 = __ocml_native_exp2_f32(m0 - mm);
      float e1 = __ocml_native_exp2_f32(m1 - mm);
      float inv = 1.f / (l0 * e0 + l1 * e1);
      float w0 = e0 * inv, w1 = e1 * inv;
#pragma unroll
      for (int nb = 0; nb < 4; ++nb) {
        int col = hh * 64 + nb * 16 + i;
        Y[rowA + (size_t)r * C_DIM + col] =
            f2bf(ya[nb][r] * w0 + Ylds[4 * g + r][nb * 16 + i] * w1);
      }
    }
    size_t rowB = rowA + (size_t)16 * C_DIM;
#pragma unroll
    for (int r = 0; r < 4; ++r) {
      float m0 = __shfl(mB, 4 * g + r);
      float l0 = __shfl(lB, 4 * g + r);
      float m1 = Mlds[16 + 4 * g + r];
      float l1 = Llds[16 + 4 * g + r];
      float mm = fmaxf(m0, m1);
      float e0 = __ocml_native_exp2_f32(m0 - mm);
      float e1 = __ocml_native_exp2_f32(m1 - mm);
      float inv = 1.f / (l0 * e0 + l1 * e1);
      float w0 = e0 * inv, w1 = e1 * inv;
#pragma unroll
      for (int nb = 0; nb < 4; ++nb) {
        int col = hh * 64 + nb * 16 + i;
        Y[rowB + (size_t)r * C_DIM + col] =
            f2bf(yb[nb][r] * w0 + Ylds[16 + 4 * g + r][nb * 16 + i] * w1);
      }
    }
  }
}

extern "C" void kernel_launch(void* const* d_in, const int* in_sizes, int n_in,
                              void* d_out, int out_size, void* d_ws, size_t ws_size,
                              hipStream_t stream) {
  const float* x      = (const float*)d_in[0];
  const float* W_attn = (const float*)d_in[1];
  const float* b_attn = (const float*)d_in[2];
  const float* W_proj = (const float*)d_in[3];
  const float* b_proj = (const float*)d_in[4];
  float* out = (float*)d_out;

  unsigned short* Wkt  = (unsigned short*)d_ws;                 // 1024x1024 bf16
  unsigned short* Wpt  = Wkt + (size_t)1024 * 1024;             // 1024x1024 bf16
  unsigned short* Khb  = Wpt + (size_t)1024 * 1024;             // [64][2048][64] bf16
  unsigned short* Ybuf = Khb + (size_t)8192 * 1024;             // 8192x1024 bf16
  unsigned short* Vtb  = Ybuf + (size_t)8192 * 1024;            // [64][64][2048] bf16
  unsigned short* xb   = Ybuf;  // reuse: xb dead before attn writes Ybuf

  // merged prep: x->bf16 + both weight transposes in one launch
  prep<<<dim3(12288), 256, 0, stream>>>(x, xb, W_attn, Wkt, W_proj, Wpt);

  // K (head-blocked) + V^T = xb @ Wk + b_attn[C:2C]
  gemm_xw<<<dim3(64, 8), 256, 0, stream>>>(xb, Wkt, b_attn + 1024, Khb, Vtb);

  // y = causal_attn(K,K,K): frozen r13 dataflow, 6 waves/SIMD residency
  attn_fwd<<<dim3(4096), 128, 0, stream>>>(Khb, Vtb, Ybuf);

  // out = y @ Wp + b_proj
  gemm_yw<<<dim3(64, 8), 256, 0, stream>>>(Ybuf, Wpt, b_proj, out);
}

// Round 26
// 192.570 us; speedup vs baseline: 1.6622x; 1.6622x over previous
//
#include <hip/hip_runtime.h>

#define T_SEQ 2048
#define C_DIM 1024
#define HD 64

typedef __attribute__((ext_vector_type(8))) short short8;
typedef __attribute__((ext_vector_type(4))) float f32x4;
typedef __attribute__((ext_vector_type(4))) unsigned int uint4v;

extern "C" __device__ float __ocml_native_exp2_f32(float);

__device__ __forceinline__ unsigned short f2bf(float f) {
  unsigned int u = __builtin_bit_cast(unsigned int, f);
  u += 0x7fffu + ((u >> 16) & 1u);
  return (unsigned short)(u >> 16);
}

__device__ __forceinline__ unsigned cvt_pk_bf16(float lo, float hi) {
  unsigned r;
  asm("v_cvt_pk_bf16_f32 %0, %1, %2" : "=v"(r) : "v"(lo), "v"(hi));
  return r;
}

// async global->LDS, 16B per lane. LDS dest = wave-uniform base + lane*16.
__device__ __forceinline__ void gload_lds16(const void* g, void* l) {
  __builtin_amdgcn_global_load_lds(
      (const __attribute__((address_space(1))) void*)g,
      (__attribute__((address_space(3))) void*)l, 16, 0, 0);
}

// ---- merged prep: blocks [0,4096) conv x->bf16; [4096,8192) transpose
// W_attn K-slice; [8192,12288) transpose W_proj. Branch is block-uniform.
__global__ __launch_bounds__(256) void prep(
    const float* __restrict__ x, unsigned short* __restrict__ xb,
    const float* __restrict__ W_attn, unsigned short* __restrict__ Wkt,
    const float* __restrict__ W_proj, unsigned short* __restrict__ Wpt) {
  int b = blockIdx.x;
  if (b < 4096) {
    size_t idx = ((size_t)b * 256 + threadIdx.x) * 8;
    const f32x4* p = (const f32x4*)(x + idx);
    f32x4 a = p[0], c = p[1];
    short8 s;
#pragma unroll
    for (int i = 0; i < 4; ++i) {
      s[i]     = (short)f2bf(a[i]);
      s[i + 4] = (short)f2bf(c[i]);
    }
    *(short8*)(xb + idx) = s;
  } else {
    __shared__ float tile[16][17];
    int b2 = b - 4096;
    const float* src;
    unsigned short* dst;
    int src_ld, col_off;
    if (b2 < 4096) { src = W_attn; dst = Wkt; src_ld = 3072; col_off = 1024; }
    else { b2 -= 4096; src = W_proj; dst = Wpt; src_ld = 1024; col_off = 0; }
    const int tx = threadIdx.x & 15, ty = threadIdx.x >> 4;
    const int bx = b2 & 63, by = b2 >> 6;
    int n = bx * 16 + tx;                    // src col (contiguous read)
    int k = by * 16 + ty;                    // src row
    tile[ty][tx] = src[(size_t)k * src_ld + col_off + n];
    __syncthreads();
    int nn = bx * 16 + ty;                   // dst row
    int kk = by * 16 + tx;                   // dst col (contiguous write)
    dst[(size_t)nn * C_DIM + kk] = f2bf(tile[tx][ty]);
  }
}

// ---- GEMM1: Khb[bh][t][d] and Vt[bh][d][t] (bf16) = xb(bf16) @ Wkt^T + bias
// Double-buffered global_load_lds staging, ONE barrier per K-step.
__global__ __launch_bounds__(256) void gemm_xw(
    const unsigned short* __restrict__ A, const unsigned short* __restrict__ Bt,
    const float* __restrict__ bias, unsigned short* __restrict__ out,
    unsigned short* __restrict__ vt) {
  __shared__ unsigned short Als[2][128 * 32];
  __shared__ unsigned short Bls[2][128 * 32];
  const int tid = threadIdx.x;
  const int l = tid & 63, w = tid >> 6;
  const int wr = w >> 1, wc = w & 1;
  const int rb = blockIdx.x * 128, cb = blockIdx.y * 128;
  const int brow = tid >> 2, bhalf = (tid & 3) * 8;
  f32x4 acc[4][4] = {};

#define STAGE_XW(BUF, KB)                                                     \
  do {                                                                        \
    gload_lds16(A + (size_t)(rb + brow) * 1024 + (KB) + bhalf,                \
                &Als[BUF][(size_t)w * 512]);                                  \
    gload_lds16(A + (size_t)(rb + 64 + brow) * 1024 + (KB) + bhalf,           \
                &Als[BUF][2048 + (size_t)w * 512]);                           \
    gload_lds16(Bt + (size_t)(cb + brow) * 1024 + (KB) + bhalf,               \
                &Bls[BUF][(size_t)w * 512]);                                  \
    gload_lds16(Bt + (size_t)(cb + 64 + brow) * 1024 + (KB) + bhalf,          \
                &Bls[BUF][2048 + (size_t)w * 512]);                           \
  } while (0)

  STAGE_XW(0, 0);
  int cur = 0;
  for (int kb = 0; kb < 1024; kb += 32) {
    __syncthreads();                       // drains buf[cur] loads; fences reads
    if (kb + 32 < 1024) STAGE_XW(cur ^ 1, kb + 32);
    short8 af[4], bfr[4];
#pragma unroll
    for (int m = 0; m < 4; ++m)
      af[m] = *(const short8*)&Als[cur][(wr * 64 + m * 16 + (l & 15)) * 32 + (l >> 4) * 8];
#pragma unroll
    for (int n = 0; n < 4; ++n)
      bfr[n] = *(const short8*)&Bls[cur][(wc * 64 + n * 16 + (l & 15)) * 32 + (l >> 4) * 8];
#pragma unroll
    for (int m = 0; m < 4; ++m)
#pragma unroll
      for (int n = 0; n < 4; ++n)
        acc[m][n] = __builtin_amdgcn_mfma_f32_16x16x32_bf16(af[m], bfr[n], acc[m][n], 0, 0, 0);
    cur ^= 1;
  }
#undef STAGE_XW

  const int rg = (l >> 4) * 4, cg = l & 15;
#pragma unroll
  for (int m = 0; m < 4; ++m)
#pragma unroll
    for (int n = 0; n < 4; ++n) {
      int col = cb + wc * 64 + n * 16 + cg;
      float bv = bias[col];
      int row0 = rb + wr * 64 + m * 16 + rg;
      unsigned short e0 = f2bf(acc[m][n][0] + bv);
      unsigned short e1 = f2bf(acc[m][n][1] + bv);
      unsigned short e2 = f2bf(acc[m][n][2] + bv);
      unsigned short e3 = f2bf(acc[m][n][3] + bv);
      size_t bhd = (size_t)((row0 >> 11) * 16 + (col >> 6));
      size_t kidx = (bhd * T_SEQ + (row0 & 2047)) * HD + (col & 63);
      out[kidx]          = e0;
      out[kidx + HD]     = e1;
      out[kidx + 2 * HD] = e2;
      out[kidx + 3 * HD] = e3;
      unsigned long long pv = (unsigned long long)e0 | ((unsigned long long)e1 << 16)
                            | ((unsigned long long)e2 << 32) | ((unsigned long long)e3 << 48);
      *(unsigned long long*)&vt[(bhd * HD + (col & 63)) * T_SEQ + (row0 & 2047)] = pv;
    }
}

// ---- GEMM2: out[8192][1024] (f32) = y(bf16) @ Wpt^T + bias
// Double-buffered global_load_lds staging, ONE barrier per K-step.
__global__ __launch_bounds__(256) void gemm_yw(
    const unsigned short* __restrict__ A, const unsigned short* __restrict__ Bt,
    const float* __restrict__ bias, float* __restrict__ out) {
  __shared__ unsigned short Als[2][128 * 32];
  __shared__ unsigned short Bls[2][128 * 32];
  const int tid = threadIdx.x;
  const int l = tid & 63, w = tid >> 6;
  const int wr = w >> 1, wc = w & 1;
  const int rb = blockIdx.x * 128, cb = blockIdx.y * 128;
  const int brow = tid >> 2, bhalf = (tid & 3) * 8;
  f32x4 acc[4][4] = {};

#define STAGE_YW(BUF, KB)                                                     \
  do {                                                                        \
    gload_lds16(A + (size_t)(rb + brow) * 1024 + (KB) + bhalf,                \
                &Als[BUF][(size_t)w * 512]);                                  \
    gload_lds16(A + (size_t)(rb + 64 + brow) * 1024 + (KB) + bhalf,           \
                &Als[BUF][2048 + (size_t)w * 512]);                           \
    gload_lds16(Bt + (size_t)(cb + brow) * 1024 + (KB) + bhalf,               \
                &Bls[BUF][(size_t)w * 512]);                                  \
    gload_lds16(Bt + (size_t)(cb + 64 + brow) * 1024 + (KB) + bhalf,          \
                &Bls[BUF][2048 + (size_t)w * 512]);                           \
  } while (0)

  STAGE_YW(0, 0);
  int cur = 0;
  for (int kb = 0; kb < 1024; kb += 32) {
    __syncthreads();
    if (kb + 32 < 1024) STAGE_YW(cur ^ 1, kb + 32);
    short8 af[4], bfr[4];
#pragma unroll
    for (int m = 0; m < 4; ++m)
      af[m] = *(const short8*)&Als[cur][(wr * 64 + m * 16 + (l & 15)) * 32 + (l >> 4) * 8];
#pragma unroll
    for (int n = 0; n < 4; ++n)
      bfr[n] = *(const short8*)&Bls[cur][(wc * 64 + n * 16 + (l & 15)) * 32 + (l >> 4) * 8];
#pragma unroll
    for (int m = 0; m < 4; ++m)
#pragma unroll
      for (int n = 0; n < 4; ++n)
        acc[m][n] = __builtin_amdgcn_mfma_f32_16x16x32_bf16(af[m], bfr[n], acc[m][n], 0, 0, 0);
    cur ^= 1;
  }
#undef STAGE_YW

  const int rg = (l >> 4) * 4, cg = l & 15;
#pragma unroll
  for (int m = 0; m < 4; ++m)
#pragma unroll
    for (int n = 0; n < 4; ++n) {
      int col = cb + wc * 64 + n * 16 + cg;
      float bv = bias[col];
#pragma unroll
      for (int r = 0; r < 4; ++r) {
        int row = rb + wr * 64 + m * 16 + rg + r;
        out[(size_t)row * 1024 + col] = acc[m][n][r] + bv;
      }
    }
}

// ---- Flash attention: FROZEN r13 dataflow, LB(128,4) (VGPR 64, no spill).
__device__ __forceinline__ void sm_group(
    f32x4 (&s)[4], int qq, int kvb, bool needmask, int g,
    float& mrun, float& lrun, f32x4 (&yacc)[4],
    int src01, int src23, bool hi2, short8 (&pa)[2]) {
  if (needmask) {
    const int lim = qq - kvb;
#pragma unroll
    for (int b = 0; b < 4; ++b)
#pragma unroll
      for (int r = 0; r < 4; ++r)
        if (16 * b + 4 * g + r > lim) s[b][r] = -INFINITY;
  }
  float mt = fmaxf(fmaxf(s[0][0], s[0][1]), fmaxf(s[0][2], s[0][3]));
#pragma unroll
  for (int b = 1; b < 4; ++b)
    mt = fmaxf(mt, fmaxf(fmaxf(s[b][0], s[b][1]), fmaxf(s[b][2], s[b][3])));
  mt = fmaxf(mt, __shfl_xor(mt, 16));
  mt = fmaxf(mt, __shfl_xor(mt, 32));
  if (!__all(mt <= mrun + 11.5416f)) {   // 8 nats in log2 units
    float mn = fmaxf(mrun, mt);
    float al = __ocml_native_exp2_f32(mrun - mn);
    mrun = mn;
    lrun *= al;
    float a0 = __shfl(al, 4 * g + 0);
    float a1 = __shfl(al, 4 * g + 1);
    float a2 = __shfl(al, 4 * g + 2);
    float a3 = __shfl(al, 4 * g + 3);
#pragma unroll
    for (int nb = 0; nb < 4; ++nb) {
      yacc[nb][0] *= a0; yacc[nb][1] *= a1;
      yacc[nb][2] *= a2; yacc[nb][3] *= a3;
    }
  }
  float ps = 0.f;
  unsigned pk[4][2];
#pragma unroll
  for (int b = 0; b < 4; ++b) {
    float p0 = __ocml_native_exp2_f32(s[b][0] - mrun);
    float p1 = __ocml_native_exp2_f32(s[b][1] - mrun);
    float p2 = __ocml_native_exp2_f32(s[b][2] - mrun);
    float p3 = __ocml_native_exp2_f32(s[b][3] - mrun);
    ps += (p0 + p1) + (p2 + p3);
    pk[b][0] = cvt_pk_bf16(p0, p1);
    pk[b][1] = cvt_pk_bf16(p2, p3);
  }
  ps += __shfl_xor(ps, 16);
  ps += __shfl_xor(ps, 32);
  lrun += ps;
  {
    unsigned x0a = (unsigned)__shfl((int)pk[0][0], src01);
    unsigned x1a = (unsigned)__shfl((int)pk[1][0], src01);
    unsigned x0b = (unsigned)__shfl((int)pk[0][1], src01);
    unsigned x1b = (unsigned)__shfl((int)pk[1][1], src01);
    unsigned y0a = (unsigned)__shfl((int)pk[0][0], src23);
    unsigned y1a = (unsigned)__shfl((int)pk[1][0], src23);
    unsigned y0b = (unsigned)__shfl((int)pk[0][1], src23);
    unsigned y1b = (unsigned)__shfl((int)pk[1][1], src23);
    uint4v u;
    u.x = hi2 ? x1a : x0a;
    u.y = hi2 ? x1b : x0b;
    u.z = hi2 ? y1a : y0a;
    u.w = hi2 ? y1b : y0b;
    pa[0] = __builtin_bit_cast(short8, u);
  }
  {
    unsigned x0a = (unsigned)__shfl((int)pk[2][0], src01);
    unsigned x1a = (unsigned)__shfl((int)pk[3][0], src01);
    unsigned x0b = (unsigned)__shfl((int)pk[2][1], src01);
    unsigned x1b = (unsigned)__shfl((int)pk[3][1], src01);
    unsigned y0a = (unsigned)__shfl((int)pk[2][0], src23);
    unsigned y1a = (unsigned)__shfl((int)pk[3][0], src23);
    unsigned y0b = (unsigned)__shfl((int)pk[2][1], src23);
    unsigned y1b = (unsigned)__shfl((int)pk[3][1], src23);
    uint4v u;
    u.x = hi2 ? x1a : x0a;
    u.y = hi2 ? x1b : x0b;
    u.z = hi2 ? y1a : y0a;
    u.w = hi2 ? y1b : y0b;
    pa[1] = __builtin_bit_cast(short8, u);
  }
}

__global__ __launch_bounds__(128, 4) void attn_fwd(
    const unsigned short* __restrict__ Khb, const unsigned short* __restrict__ Vt,
    unsigned short* __restrict__ Y) {
  const int id = blockIdx.x;
  const int xcd = id & 7;
  const int r8  = id >> 3;             // 0..511
  const int bh  = xcd * 8 + (r8 & 7);
  const int chunk = 63 - (r8 >> 3);    // descending work within each XCD
  const int tid = threadIdx.x;
  const int w = tid >> 6;              // kv-split half
  const int l = tid & 63;
  const int i = l & 15, g = l >> 4;
  const unsigned short* kbase = Khb + (size_t)bh * T_SEQ * HD;
  const unsigned short* vbase = Vt + (size_t)bh * HD * T_SEQ;

  const int q0 = chunk * 32;
  const int qA = q0 + i, qB = q0 + 16 + i;
  const int nt = (q0 + 31) / 64 + 1;
  const int half = (nt + 1) >> 1;
  const int tBeg = w ? half : 0;
  const int tEnd = w ? nt : half;

  __shared__ float Ylds[32][68];
  __shared__ float Mlds[32];
  __shared__ float Llds[32];

  short8 qa0 = *(const short8*)(kbase + (size_t)qA * HD + g * 8);
  short8 qa1 = *(const short8*)(kbase + (size_t)qA * HD + 32 + g * 8);
  short8 qb0 = *(const short8*)(kbase + (size_t)qB * HD + g * 8);
  short8 qb1 = *(const short8*)(kbase + (size_t)qB * HD + 32 + g * 8);

  f32x4 ya[4] = {}, yb[4] = {};
  float mA = -INFINITY, lA = 0.f, mB = -INFINITY, lB = 0.f;

  const int src01 = i + ((g & 1) << 5);
  const int src23 = src01 + 16;
  const bool hi2 = (g >> 1) != 0;
  const float SCL = 0.18033688f;   // 0.125 * log2(e)

#pragma unroll 2
  for (int t = tBeg; t < tEnd; ++t) {
    const int kvb = t * 64;
    f32x4 sa[4], sb[4];
#pragma unroll
    for (int b = 0; b < 4; ++b) {
      const unsigned short* kp = kbase + (size_t)(kvb + 16 * b + i) * HD + g * 8;
      short8 k0 = *(const short8*)kp;
      short8 k1 = *(const short8*)(kp + 32);
      f32x4 acc = {};
      acc = __builtin_amdgcn_mfma_f32_16x16x32_bf16(k0, qa0, acc, 0, 0, 0);
      acc = __builtin_amdgcn_mfma_f32_16x16x32_bf16(k1, qa1, acc, 0, 0, 0);
      sa[b] = acc;
      f32x4 acc2 = {};
      acc2 = __builtin_amdgcn_mfma_f32_16x16x32_bf16(k0, qb0, acc2, 0, 0, 0);
      acc2 = __builtin_amdgcn_mfma_f32_16x16x32_bf16(k1, qb1, acc2, 0, 0, 0);
      sb[b] = acc2;
    }
#pragma unroll
    for (int b = 0; b < 4; ++b)
#pragma unroll
      for (int r = 0; r < 4; ++r) { sa[b][r] *= SCL; sb[b][r] *= SCL; }

    const bool needmask = (kvb + 63 > q0);
    short8 paA[2], paB[2];
    sm_group(sa, qA, kvb, needmask, g, mA, lA, ya, src01, src23, hi2, paA);
    sm_group(sb, qB, kvb, needmask, g, mB, lB, yb, src01, src23, hi2, paB);

#pragma unroll
    for (int c = 0; c < 2; ++c)
#pragma unroll
      for (int nb = 0; nb < 4; ++nb) {
        short8 vf = *(const short8*)(vbase + (size_t)(nb * 16 + i) * T_SEQ + kvb + c * 32 + g * 8);
        ya[nb] = __builtin_amdgcn_mfma_f32_16x16x32_bf16(paA[c], vf, ya[nb], 0, 0, 0);
        yb[nb] = __builtin_amdgcn_mfma_f32_16x16x32_bf16(paB[c], vf, yb[nb], 0, 0, 0);
      }
  }

  // wave1 deposits unnormalized partials
  if (w == 1) {
#pragma unroll
    for (int nb = 0; nb < 4; ++nb)
#pragma unroll
      for (int r = 0; r < 4; ++r) {
        Ylds[4 * g + r][nb * 16 + i]      = ya[nb][r];
        Ylds[16 + 4 * g + r][nb * 16 + i] = yb[nb][r];
      }
    if (l < 16) {
      Mlds[l]      = mA;
      Llds[l]      = lA;
      Mlds[16 + l] = mB;
      Llds[16 + l] = lB;
    }
  }
  __syncthreads();
  // wave0 merges and stores
  if (w == 0) {
    const int bb = bh >> 4, hh = bh & 15;
    size_t rowA = ((size_t)bb * T_SEQ + q0 + 4 * g) * C_DIM;
#pragma unroll
    for (int r = 0; r < 4; ++r) {
      float m0 = __shfl(mA, 4 * g + r);
      float l0 = __shfl(lA, 4 * g + r);
      float m1 = Mlds[4 * g + r];
      float l1 = Llds[4 * g + r];
      float mm = fmaxf(m0, m1);
      float e0 = __ocml_native_exp2_f32(m0 - mm);
      float e1 = __ocml_native_exp2_f32(m1 - mm);
      float inv = 1.f / (l0 * e0 + l1 * e1);
      float w0 = e0 * inv, w1 = e1 * inv;
#pragma unroll
      for (int nb = 0; nb < 4; ++nb) {
        int col = hh * 64 + nb * 16 + i;
        Y[rowA + (size_t)r * C_DIM + col] =
            f2bf(ya[nb][r] * w0 + Ylds[4 * g + r][nb * 16 + i] * w1);
      }
    }
    size_t rowB = rowA + (size_t)16 * C_DIM;
#pragma unroll
    for (int r = 0; r < 4; ++r) {
      float m0 = __shfl(mB, 4 * g + r);
      float l0 = __shfl(lB, 4 * g + r);
      float m1 = Mlds[16 + 4 * g + r];
      float l1 = Llds[16 + 4 * g + r];
      float mm = fmaxf(m0, m1);
      float e0 = __ocml_native_exp2_f32(m0 - mm);
      float e1 = __ocml_native_exp2_f32(m1 - mm);
      float inv = 1.f / (l0 * e0 + l1 * e1);
      float w0 = e0 * inv, w1 = e1 * inv;
#pragma unroll
      for (int nb = 0; nb < 4; ++nb) {
        int col = hh * 64 + nb * 16 + i;
        Y[rowB + (size_t)r * C_DIM + col] =
            f2bf(yb[nb][r] * w0 + Ylds[16 + 4 * g + r][nb * 16 + i] * w1);
      }
    }
  }
}

extern "C" void kernel_launch(void* const* d_in, const int* in_sizes, int n_in,
                              void* d_out, int out_size, void* d_ws, size_t ws_size,
                              hipStream_t stream) {
  const float* x      = (const float*)d_in[0];
  const float* W_attn = (const float*)d_in[1];
  const float* b_attn = (const float*)d_in[2];
  const float* W_proj = (const float*)d_in[3];
  const float* b_proj = (const float*)d_in[4];
  float* out = (float*)d_out;

  unsigned short* Wkt  = (unsigned short*)d_ws;                 // 1024x1024 bf16
  unsigned short* Wpt  = Wkt + (size_t)1024 * 1024;             // 1024x1024 bf16
  unsigned short* Khb  = Wpt + (size_t)1024 * 1024;             // [64][2048][64] bf16
  unsigned short* Ybuf = Khb + (size_t)8192 * 1024;             // 8192x1024 bf16
  unsigned short* Vtb  = Ybuf + (size_t)8192 * 1024;            // [64][64][2048] bf16
  unsigned short* xb   = Ybuf;  // reuse: xb dead before attn writes Ybuf

  // merged prep: x->bf16 + both weight transposes in one launch
  prep<<<dim3(12288), 256, 0, stream>>>(x, xb, W_attn, Wkt, W_proj, Wpt);

  // K (head-blocked) + V^T = xb @ Wk + b_attn[C:2C]
  gemm_xw<<<dim3(64, 8), 256, 0, stream>>>(xb, Wkt, b_attn + 1024, Khb, Vtb);

  // y = causal_attn(K,K,K): frozen r13 dataflow
  attn_fwd<<<dim3(4096), 128, 0, stream>>>(Khb, Vtb, Ybuf);

  // out = y @ Wp + b_proj
  gemm_yw<<<dim3(64, 8), 256, 0, stream>>>(Ybuf, Wpt, b_proj, out);
}